// Round 9
// baseline (427.043 us; speedup 1.0000x reference)
//
#include <hip/hip_runtime.h>

#define T_STEPS 256
#define HID 40
#define EPB 16
#define NTHR 512
#define AST 136   // A0/A1 row stride (shorts); 272B, mod 128 = 16 -> even bank tiling
#define XST 72    // Ax row stride (shorts)

typedef __attribute__((ext_vector_type(8))) short bf16x8;
typedef __attribute__((ext_vector_type(4))) float f32x4;

__device__ __forceinline__ unsigned short bf16_rne(float v) {
    unsigned int x = __float_as_uint(v);
    unsigned int r = x + 0x7FFFu + ((x >> 16) & 1u);
    return (unsigned short)(r >> 16);
}
__device__ __forceinline__ float bf16f(unsigned short h) {
    return __uint_as_float(((unsigned int)h) << 16);
}
__device__ __forceinline__ float sigm(float v)  { return 1.0f / (1.0f + __expf(-v)); }
__device__ __forceinline__ float tanh_f(float v){ return 1.0f - 2.0f / (__expf(2.0f * v) + 1.0f); }

// Roles swapped vs r7/r8: weights are the A-operand (M=positions), state is the
// B-operand (N=elems). C layout row=quad*4+reg, col=lane&15 => lane (e,q) of
// tile T holds [r_pre, z_pre, nx, nh] of unit 4T+q for elem e entirely in regs.
#define MF(A_, B_, C_) C_ = __builtin_amdgcn_mfma_f32_16x16x32_bf16(A_, B_, C_, 0, 0, 0)
#define PINV(v) asm volatile("" : "+v"(v))

// k'-space (3K, zero-padded to 32*c chunks): [0,2K) = (hi,lo)-interleaved state
// pairs vs wh; [2K,3K) = hi2 vs wl. 3-term split: wh*hi + wh*lo + wl*hi,
// error O(2^-16) (r7/r8-proven, absmax 2e-3). row<0 => zero frag.
__device__ bf16x8 wfrag(const float* W, int stride, int K, int row, int c, int qrow) {
    bf16x8 f;
    #pragma unroll
    for (int j = 0; j < 8; ++j) f[j] = 0;
    if (row < 0) return f;
    #pragma unroll
    for (int j = 0; j < 8; ++j) {
        const int kp = 32 * c + qrow * 8 + j;
        if (kp < 2 * K) {
            f[j] = (short)bf16_rne(W[row * stride + (kp >> 1)]);
        } else if (kp < 3 * K) {
            const float w = W[row * stride + (kp - 2 * K)];
            const unsigned short hb = bf16_rne(w);
            f[j] = (short)bf16_rne(w - bf16f(hb));
        }
    }
    return f;
}

__global__ __launch_bounds__(NTHR, 2)
void gru2_kernel(const float* __restrict__ x,
                 const float* __restrict__ Wih0, const float* __restrict__ Whh0,
                 const float* __restrict__ bih0, const float* __restrict__ bhh0,
                 const float* __restrict__ Wih1, const float* __restrict__ Whh1,
                 const float* __restrict__ bih1, const float* __restrict__ bhh1,
                 float* __restrict__ out)
{
    __shared__ __align__(16) unsigned short A0[EPB][AST];  // h0: [hi,lo pairs 0..79 | hi2 80..119 | 0-pad]
    __shared__ __align__(16) unsigned short A1[EPB][AST];  // h1
    __shared__ __align__(16) unsigned short Ax[EPB][XST];  // x:  pairs 0..31 | hi2 32..47 | 0-pad

    const int tid  = threadIdx.x;
    const int wid  = tid >> 6;
    const int l    = tid & 63;
    const int col  = l & 15;     // elem (B-frag n, C col)
    const int qrow = l >> 4;
    const int pm   = l & 15;     // A-frag position-in-tile (m)
    const int ps   = pm & 3;     // slot of A-row this lane holds
    const int pu   = pm >> 2;    // unit-in-tile of A-row
    const int e0   = blockIdx.x * EPB;

    const bool isL1 = wid >= 4;
    const int  lw   = wid & 3;
    const int  NT   = (lw < 2) ? 3 : 2;                 // tiles per wave (10 per layer)
    const int  T0   = (lw < 2) ? lw * 3 : 6 + (lw - 2) * 2;

    const float* Whh = isL1 ? Whh1 : Whh0;
    const float* Wih = isL1 ? Wih1 : Wih0;
    const float* bih = isL1 ? bih1 : bih0;
    const float* bhh = isL1 ? bhh1 : bhh0;
    const int WST = isL1 ? 40 : 16;   // Wih row stride
    const int KX  = isL1 ? 40 : 16;   // input-part source length

    // ---- build weight A-frags + bias C-inits (one-time, pinned) ----
    bf16x8 Fh00,Fh01,Fh02,Fh03, Fh10,Fh11,Fh12,Fh13, Fh20,Fh21,Fh22,Fh23;
    bf16x8 Fx00,Fx01,Fx02,Fx03, Fx10,Fx11,Fx12,Fx13, Fx20,Fx21,Fx22,Fx23;
    float bb00,bb01,bb02,bb03, bb10,bb11,bb12,bb13, bb20,bb21,bb22,bb23;

#define BUILDT(J, TT, DEAD) { \
    const int uA = 4 * (TT) + pu; \
    const int rH = ((DEAD) || ps == 2) ? -1 : (ps == 0 ? uA : ps == 1 ? 40 + uA : 80 + uA); \
    const int rX = ((DEAD) || ps == 3) ? -1 : (ps == 0 ? uA : ps == 1 ? 40 + uA : 80 + uA); \
    Fh##J##0 = wfrag(Whh, 40, 40, rH, 0, qrow); \
    Fh##J##1 = wfrag(Whh, 40, 40, rH, 1, qrow); \
    Fh##J##2 = wfrag(Whh, 40, 40, rH, 2, qrow); \
    Fh##J##3 = wfrag(Whh, 40, 40, rH, 3, qrow); \
    Fx##J##0 = wfrag(Wih, WST, KX, rX, 0, qrow); \
    Fx##J##1 = wfrag(Wih, WST, KX, rX, 1, qrow); \
    Fx##J##2 = wfrag(Wih, WST, KX, rX, 2, qrow); \
    Fx##J##3 = wfrag(Wih, WST, KX, rX, 3, qrow); \
    const int uc = 4 * (TT) + qrow; \
    bb##J##0 = (DEAD) ? 0.f : bih[uc] + bhh[uc]; \
    bb##J##1 = (DEAD) ? 0.f : bih[40 + uc] + bhh[40 + uc]; \
    bb##J##2 = (DEAD) ? 0.f : bih[80 + uc]; \
    bb##J##3 = (DEAD) ? 0.f : bhh[80 + uc]; }

    BUILDT(0, T0,     0)
    BUILDT(1, T0 + 1, 0)
    BUILDT(2, (NT == 3) ? T0 + 2 : T0, (NT == 3) ? 0 : 1)

    PINV(Fh00); PINV(Fh01); PINV(Fh02); PINV(Fh03);
    PINV(Fh10); PINV(Fh11); PINV(Fh12); PINV(Fh13);
    PINV(Fh20); PINV(Fh21); PINV(Fh22); PINV(Fh23);
    PINV(Fx00); PINV(Fx01); PINV(Fx02); PINV(Fx03);
    PINV(Fx10); PINV(Fx11); PINV(Fx12); PINV(Fx13);
    PINV(Fx20); PINV(Fx21); PINV(Fx22); PINV(Fx23);
    asm volatile("" : "+v"(bb00), "+v"(bb01), "+v"(bb02), "+v"(bb03));
    asm volatile("" : "+v"(bb10), "+v"(bb11), "+v"(bb12), "+v"(bb13));
    asm volatile("" : "+v"(bb20), "+v"(bb21), "+v"(bb22), "+v"(bb23));

    // C-side units + state writeback pointer (self-layer buffer)
    const int U0 = 4 * T0 + qrow, U1 = U0 + 4, U2 = U0 + 8;
    unsigned short* wpa = (isL1 ? &A1[0][0] : &A0[0][0]) + col * AST;
    float h0_ = 0.f, h1_ = 0.f, h2_ = 0.f;

    // B-frag (state) read pointers: self-h and input sources
    const unsigned short* shp = (isL1 ? &A1[0][0] : &A0[0][0]) + col * AST + qrow * 8;
    const unsigned short* sxp = isL1 ? (&A0[0][0] + col * AST + qrow * 8)
                                     : (&Ax[0][0] + col * XST + qrow * 8);

    // ---- init: zero buffers (pads MUST be 0), stage x[0], preload x[1] ----
    for (int idx = tid; idx < EPB * AST; idx += NTHR) { (&A0[0][0])[idx] = 0; (&A1[0][0])[idx] = 0; }
    for (int idx = tid; idx < EPB * XST; idx += NTHR) (&Ax[0][0])[idx] = 0;
    __syncthreads();
    const bool xth = tid < 256;
    const int xe = tid >> 4, xk = tid & 15;
    const float* xrow = x + (size_t)(e0 + xe) * (T_STEPS * 16) + xk;
    float xold = 0.f;
    if (xth) {
        const float v = xrow[0];
        const unsigned short hb = bf16_rne(v);
        const unsigned short lb = bf16_rne(v - bf16f(hb));
        *(unsigned int*)(&Ax[xe][2 * xk]) = (unsigned int)hb | ((unsigned int)lb << 16);
        Ax[xe][32 + xk] = hb;
        xold = xrow[16];
    }
    __syncthreads();

    bf16x8 Zf;
    #pragma unroll
    for (int j = 0; j < 8; ++j) Zf[j] = 0;

#define TILE(J, U, H) { \
    f32x4 c = (f32x4){bb##J##0, bb##J##1, bb##J##2, bb##J##3}; \
    MF(Fh##J##0, SH0, c); MF(Fh##J##1, SH1, c); MF(Fh##J##2, SH2, c); MF(Fh##J##3, SH3, c); \
    MF(Fx##J##0, SX0, c); MF(Fx##J##1, SX1, c); \
    if (isL1) { MF(Fx##J##2, SX2, c); MF(Fx##J##3, SX3, c); } \
    if (active) { \
        const float r_ = sigm(c[0]); \
        const float z_ = sigm(c[1]); \
        const float n_ = tanh_f(c[2] + r_ * c[3]); \
        H = (1.0f - z_) * n_ + z_ * H; \
        const unsigned short hb_ = bf16_rne(H); \
        const unsigned short lb_ = bf16_rne(H - bf16f(hb_)); \
        *(unsigned int*)(wpa + 2 * (U)) = (unsigned int)hb_ | ((unsigned int)lb_ << 16); \
        wpa[80 + (U)] = hb_; } }

    for (int t = 0; t <= T_STEPS; ++t) {
        // prefetch x[t+2] (HBM latency off critical path)
        float xnew = 0.f;
        if (xth && t + 2 < T_STEPS) xnew = xrow[(t + 2) * 16];

        // ---- read state B-frags (all waves), then barrier ----
        const bf16x8 SH0 = *(const bf16x8*)(shp);
        const bf16x8 SH1 = *(const bf16x8*)(shp + 32);
        const bf16x8 SH2 = *(const bf16x8*)(shp + 64);
        const bf16x8 SH3 = *(const bf16x8*)(shp + 96);
        const bf16x8 SX0 = *(const bf16x8*)(sxp);
        const bf16x8 SX1 = *(const bf16x8*)(sxp + 32);
        bf16x8 SX2 = Zf, SX3 = Zf;
        if (isL1) { SX2 = *(const bf16x8*)(sxp + 64); SX3 = *(const bf16x8*)(sxp + 96); }
        __syncthreads();   // all reads done before any h' write

        const bool active = isL1 ? (t > 0) : (t < T_STEPS);

        // ---- MFMA + in-register gate assembly + h' writeback ----
        TILE(0, U0, h0_)
        TILE(1, U1, h1_)
        if (NT == 3) TILE(2, U2, h2_)

        // stage x[t+1]
        if (xth && t < T_STEPS - 1) {
            const unsigned short hb = bf16_rne(xold);
            const unsigned short lb = bf16_rne(xold - bf16f(hb));
            *(unsigned int*)(&Ax[xe][2 * xk]) = (unsigned int)hb | ((unsigned int)lb << 16);
            Ax[xe][32 + xk] = hb;
        }
        xold = xnew;
        __syncthreads();   // writes visible before next iter's reads
    }

    // ---- h1[255] straight from registers ----
    if (isL1) {
        out[(size_t)(e0 + col) * HID + U0] = h0_;
        out[(size_t)(e0 + col) * HID + U1] = h1_;
        if (NT == 3) out[(size_t)(e0 + col) * HID + U2] = h2_;
    }
}

extern "C" void kernel_launch(void* const* d_in, const int* in_sizes, int n_in,
                              void* d_out, int out_size, void* d_ws, size_t ws_size,
                              hipStream_t stream) {
    const float* x    = (const float*)d_in[0];
    const float* Wih0 = (const float*)d_in[1];
    const float* Whh0 = (const float*)d_in[2];
    const float* bih0 = (const float*)d_in[3];
    const float* bhh0 = (const float*)d_in[4];
    const float* Wih1 = (const float*)d_in[5];
    const float* Whh1 = (const float*)d_in[6];
    const float* bih1 = (const float*)d_in[7];
    const float* bhh1 = (const float*)d_in[8];
    float* out = (float*)d_out;

    dim3 grid(4096 / EPB), block(NTHR);
    hipLaunchKernelGGL(gru2_kernel, grid, block, 0, stream,
                       x, Wih0, Whh0, bih0, bhh0, Wih1, Whh1, bih1, bhh1, out);
}